// Round 1
// baseline (345.176 us; speedup 1.0000x reference)
//
#include <hip/hip_runtime.h>

// log-ODE Neural CDE. B=32 chains, 32 windows, Heun = 2 vector-field evals
// per window. fp32 in/out, f32 accum, f16 weights/activations (v_dot2_f32_f16).
// 512 threads/block (8 waves), one block per batch element.
//
// R10 restructure: 6 barrier-phases per eval (was 8) -- the structural floor
// of the dataflow y->h1->h2->f->D1->D2->con:
//  * U-fold eliminated by linearity: P_i = W1@f_i computed directly, combined
//    with C (in REGISTERS, built once per window) via one shfl_xor(2).
//  * k-sum phase eliminated: thread t owns W3 row (t&7)*64+(t>>3), so the 8
//    contributions to k[a] sit in 8 adjacent lanes -> 3 shfl_xor, no sCon.
//  * b1/b2/b3/g_i moved LDS->registers; ph1/ph2 de-duplicated via 4-way
//    column split with own-quarter-first weight ordering (static reg indices).
#define NBATCH 32
#define LPATH  513
#define NWIN   32
#define LSIG   36
#define DSTR   136   // [dir] stride sD1/sD2 (f16) = 17 uint4: conflict-free
#define FSTR   72    // [dir] stride sFh (f16) = 9 uint4

typedef unsigned int u32;
typedef _Float16 h2 __attribute__((ext_vector_type(2)));

__device__ __forceinline__ u32 pkh(float a, float b){
  return __builtin_bit_cast(u32, __builtin_amdgcn_cvt_pkrtz(a, b));
}
__device__ __forceinline__ float dot2(u32 a, u32 b, float c){
#if __has_builtin(__builtin_amdgcn_fdot2)
  return __builtin_amdgcn_fdot2(__builtin_bit_cast(h2,a),
                                __builtin_bit_cast(h2,b), c, false);
#else
  h2 x = __builtin_bit_cast(h2,a), y = __builtin_bit_cast(h2,b);
  return c + (float)x[0]*(float)y[0] + (float)x[1]*(float)y[1];
#endif
}
__device__ __forceinline__ float tanh_fast(float x){
  float e = __expf(2.f*x);
  return 1.f - 2.f/(e+1.f);
}

extern "C" __global__ __launch_bounds__(512, 1)
void cde_kernel(const float* __restrict__ cv,
                const float* __restrict__ Wi1g, const float* __restrict__ bi1g,
                const float* __restrict__ Wi2g, const float* __restrict__ bi2g,
                const float* __restrict__ W1g,  const float* __restrict__ b1g,
                const float* __restrict__ W2g,  const float* __restrict__ b2g,
                const float* __restrict__ W3g,  const float* __restrict__ b3g,
                const float* __restrict__ Wrg,  const float* __restrict__ brg,
                const float* __restrict__ shg,
                float* __restrict__ outp)
{
  // ---- LDS (~12.5 KB) ----
  __shared__ __align__(16) float sG[NWIN*LSIG];
  __shared__ __align__(16) float sWr[256];
  __shared__ float sBr[4], sSh[1];
  __shared__ __align__(16) float sY[64];
  __shared__ float sK1[64], sLw[64];
  __shared__ __align__(16) _Float16 sYinp[64];
  __shared__ __align__(16) _Float16 sH1[128];
  __shared__ __align__(16) _Float16 sH2[128];
  __shared__ __align__(16) _Float16 sFh[8*FSTR];
  __shared__ __align__(16) _Float16 sD1[8*DSTR];
  __shared__ __align__(16) _Float16 sD2[8*DSTR];

  const int t  = threadIdx.x;        // 0..511
  const int b  = blockIdx.x;
  const int r  = t >> 2;             // 0..127 (A/B/D/E row)
  const int m  = t & 1;              // col half
  const int g  = (t >> 1) & 1;       // quarter / dir group
  const int i8 = t & 7;              // dir (C/F row-block)
  const int a8 = t >> 3;             // 0..63 (C/F col within block)
  const int p  = i8*64 + a8;         // owned W3 row (permuted for in-wave k-sum)

  // ---- init readout consts ----
  if (t < 256) sWr[t] = Wrg[t];
  if (t < 4)   sBr[t] = brg[t];
  if (t == 0)  sSh[0] = shg[0];

  // ---- depth-2 Lyndon log-signatures, one window per thread (t<32) ----
  if (t < NWIN){
    const float4* cv4 = (const float4*)cv;
    const int base = (b*LPATH + t*16)*2;
    float cur[8], pre[8], acc[8], lvw[28];
    { float4 a = cv4[base], d = cv4[base+1];
      cur[0]=a.x;cur[1]=a.y;cur[2]=a.z;cur[3]=a.w;
      cur[4]=d.x;cur[5]=d.y;cur[6]=d.z;cur[7]=d.w; }
    #pragma unroll
    for (int d=0; d<8; d++){ pre[d]=0.f; acc[d]=0.f; }
    #pragma unroll
    for (int pq=0; pq<28; pq++) lvw[pq]=0.f;
    for (int w=1; w<=16; w++){
      float nxt[8], inc[8];
      { float4 a = cv4[base+2*w], d = cv4[base+2*w+1];
        nxt[0]=a.x;nxt[1]=a.y;nxt[2]=a.z;nxt[3]=a.w;
        nxt[4]=d.x;nxt[5]=d.y;nxt[6]=d.z;nxt[7]=d.w; }
      #pragma unroll
      for (int d=0; d<8; d++) inc[d] = nxt[d]-cur[d];
      int pq=0;
      #pragma unroll
      for (int i=0; i<8; i++)
        #pragma unroll
        for (int j2=i+1; j2<8; j2++){ lvw[pq] += pre[i]*inc[j2] - pre[j2]*inc[i]; pq++; }
      #pragma unroll
      for (int d=0; d<8; d++){ acc[d]+=inc[d]; pre[d]+=inc[d]; cur[d]=nxt[d]; }
    }
    float* gd = &sG[t*LSIG];
    #pragma unroll
    for (int d=0; d<8; d++) gd[d] = acc[d];
    #pragma unroll
    for (int pq=0; pq<28; pq++) gd[8+pq] = 0.5f*lvw[pq];
  }

  // ---- y0 = Wi2 @ lipswish(Wi1 @ x0 + bi1) + bi2 ----
  if (t < 64){
    float z = bi1g[t];
    #pragma unroll
    for (int d=0; d<8; d++) z += Wi1g[t*8+d] * cv[(b*LPATH)*8 + d];
    float s = 1.f/(1.f+__expf(-z));
    sLw[t] = 0.909f*z*s;
  }
  __syncthreads();
  if (t < 64){
    float z = bi2g[t];
    #pragma unroll 8
    for (int k=0; k<64; k++) z += Wi2g[t*64+k] * sLw[k];
    sY[t] = z;
    sYinp[t] = (_Float16)z;
  }
  __syncthreads();
  if (t < 4){
    float z = sBr[t] + sSh[0];
    #pragma unroll 8
    for (int a=0; a<64; a++) z += sWr[t*64+a]*sY[a];
    outp[(b*33 + 0)*4 + t] = z;
  }

  // ---- per-thread weight registers (own-quarter-first within m-half) ----
  // w1h: cols [m*32+g*16 .. +15] in [0..7], other quarter in [8..15].
  // w2h: cols [m*64+g*32 .. +31] in [0..15], other quarter in [16..31].
  // w3r: full row p (permuted ownership).
  u32 w1h[16], w2h[32], w3r[64];
  {
    const float2* W1f2 = (const float2*)W1g;
    #pragma unroll
    for (int i=0; i<8; i++){ float2 v = W1f2[r*32 + m*16 + g*8 + i];     w1h[i]   = pkh(v.x, v.y); }
    #pragma unroll
    for (int i=0; i<8; i++){ float2 v = W1f2[r*32 + m*16 + (1-g)*8 + i]; w1h[8+i] = pkh(v.x, v.y); }
    const float2* W2f2 = (const float2*)W2g;
    #pragma unroll
    for (int i=0; i<16; i++){ float2 v = W2f2[r*64 + m*32 + g*16 + i];     w2h[i]    = pkh(v.x, v.y); }
    #pragma unroll
    for (int i=0; i<16; i++){ float2 v = W2f2[r*64 + m*32 + (1-g)*16 + i]; w2h[16+i] = pkh(v.x, v.y); }
    const float4* W3f4 = (const float4*)W3g;
    #pragma unroll
    for (int k=0; k<32; k++){
      float4 v = W3f4[p*32 + k];
      w3r[2*k]   = pkh(v.x, v.y);
      w3r[2*k+1] = pkh(v.z, v.w);
    }
  }
  const float b1r = b1g[r], b2r = b2g[r], b3r = b3g[p];

  float gi = 0.f;       // gcur[i8], per window
  float c[8][4];        // C[j][4g+k], per window, registers (static idx only)

  // One vector-field eval. mode 0: k1 (sK1, sYinp=y+k1, fused readout in A).
  // mode 1: k2 (Heun update fused in F).
  auto EVAL = [&](int mode, int s){
    __syncthreads();                          // sYinp (and sY) ready
    float dp1, dp2, fr;
    // ---- A: h1 = lipswish(W1 y + b1); fused y_s readout (mode 0) ----
    {
      if (mode == 0 && s > 0 && t >= 504 && t < 508){
        int o = t - 504;
        float z = sBr[o] + sSh[0];
        const float4* wr4 = (const float4*)&sWr[o*64];
        const float4* y4f = (const float4*)sY;
        #pragma unroll
        for (int q=0; q<16; q++){
          float4 w = wr4[q], y = y4f[q];
          z += w.x*y.x + w.y*y.y + w.z*y.z + w.w*y.w;
        }
        outp[(b*33 + s)*4 + o] = z;
      }
      const uint4* y4 = (const uint4*)sYinp;
      const int qa = m*4 + g*2;               // own quarter: 2 uint4
      uint4 A0 = y4[qa], A1 = y4[qa+1];
      float z0 = dot2(w1h[0], A0.x, 0.f), z1 = dot2(w1h[1], A0.y, 0.f);
      z0 = dot2(w1h[2], A0.z, z0); z1 = dot2(w1h[3], A0.w, z1);
      z0 = dot2(w1h[4], A1.x, z0); z1 = dot2(w1h[5], A1.y, z1);
      z0 = dot2(w1h[6], A1.z, z0); z1 = dot2(w1h[7], A1.w, z1);
      float z = z0 + z1;
      z += __shfl_xor(z, 1);                  // sum m
      z += __shfl_xor(z, 2);                  // sum g
      z += b1r;
      float sg = 1.f/(1.f+__expf(-z));
      dp1 = 0.909f*sg*(1.f + z*(1.f-sg));
      if ((t & 3) == 0) sH1[r] = (_Float16)(0.909f*z*sg);
    }
    __syncthreads();
    // ---- B: h2 = lipswish(W2 h1 + b2); quarter split ----
    {
      const uint4* h4 = (const uint4*)sH1;
      const int qb = m*8 + g*4;               // own quarter: 4 uint4
      float z0 = 0.f, z1 = 0.f;
      #pragma unroll
      for (int q=0; q<4; q++){
        uint4 v = h4[qb + q];
        z0 = dot2(w2h[4*q+0], v.x, z0); z1 = dot2(w2h[4*q+1], v.y, z1);
        z0 = dot2(w2h[4*q+2], v.z, z0); z1 = dot2(w2h[4*q+3], v.w, z1);
      }
      float z = z0 + z1;
      z += __shfl_xor(z, 1);
      z += __shfl_xor(z, 2);
      z += b2r;
      float sg = 1.f/(1.f+__expf(-z));
      dp2 = 0.909f*sg*(1.f + z*(1.f-sg));
      if ((t & 3) == 0) sH2[r] = (_Float16)(0.909f*z*sg);
    }
    __syncthreads();
    // ---- C: f = tanh(W3 h2 + b3), row p; write f16 to [dir][64] layout ----
    {
      const uint4* h4 = (const uint4*)sH2;    // wave-uniform broadcast reads
      float a0=0.f, a1=0.f, a2=0.f, a3=0.f;
      #pragma unroll
      for (int q=0; q<16; q++){
        uint4 hv = h4[q];
        a0 = dot2(w3r[4*q+0], hv.x, a0);
        a1 = dot2(w3r[4*q+1], hv.y, a1);
        a2 = dot2(w3r[4*q+2], hv.z, a2);
        a3 = dot2(w3r[4*q+3], hv.w, a3);
      }
      fr = tanh_fast((a0+a1)+(a2+a3) + b3r);
      sFh[i8*FSTR + a8] = (_Float16)fr;
    }
    __syncthreads();
    // ---- D: P_i = W1 @ f_i ; D1_j = dp1 * sum_i C[j,i] P_i (U-fold fused) ----
    {
      const uint4* f4 = (const uint4*)sFh;
      const int q0 = m*4 + g*2, q1 = m*4 + 2 - g*2;   // own / other quarter
      float P[4];
      #pragma unroll
      for (int k=0; k<4; k++){
        const uint4* fd = &f4[(4*g + k)*9];
        uint4 A0 = fd[q0], A1 = fd[q0+1], B0 = fd[q1], B1 = fd[q1+1];
        float z0 = dot2(w1h[0], A0.x, 0.f), z1 = dot2(w1h[1], A0.y, 0.f);
        z0 = dot2(w1h[2],  A0.z, z0); z1 = dot2(w1h[3],  A0.w, z1);
        z0 = dot2(w1h[4],  A1.x, z0); z1 = dot2(w1h[5],  A1.y, z1);
        z0 = dot2(w1h[6],  A1.z, z0); z1 = dot2(w1h[7],  A1.w, z1);
        z0 = dot2(w1h[8],  B0.x, z0); z1 = dot2(w1h[9],  B0.y, z1);
        z0 = dot2(w1h[10], B0.z, z0); z1 = dot2(w1h[11], B0.w, z1);
        z0 = dot2(w1h[12], B1.x, z0); z1 = dot2(w1h[13], B1.y, z1);
        z0 = dot2(w1h[14], B1.z, z0); z1 = dot2(w1h[15], B1.w, z1);
        float z = z0 + z1;
        z += __shfl_xor(z, 1);                // sum m halves -> P_i[r]
        P[k] = z;
      }
      const int own = 2*g + m;                // this lane writes j = 2*own, 2*own+1
      #pragma unroll
      for (int j=0; j<8; j++){
        float pj = c[j][0]*P[0] + c[j][1]*P[1] + c[j][2]*P[2] + c[j][3]*P[3];
        pj += __shfl_xor(pj, 2);              // add other dir-group's partial
        if ((j >> 1) == own) sD1[j*DSTR + r] = (_Float16)(dp1*pj);
      }
    }
    __syncthreads();
    // ---- E: D2_j = dp2 * (W2 @ D1_j). (r,m,g): 4 dirs x 64-col half ----
    {
      const uint4* d4 = (const uint4*)sD1;
      const int e0 = m*8 + g*4, e1 = m*8 + 4 - g*4;
      #pragma unroll
      for (int k=0; k<4; k++){
        const int dir = 4*g + k;
        const uint4* dd = &d4[dir*17];
        float z0 = 0.f, z1 = 0.f;
        #pragma unroll
        for (int q=0; q<4; q++){
          uint4 v = dd[e0 + q];
          z0 = dot2(w2h[4*q+0], v.x, z0); z1 = dot2(w2h[4*q+1], v.y, z1);
          z0 = dot2(w2h[4*q+2], v.z, z0); z1 = dot2(w2h[4*q+3], v.w, z1);
        }
        #pragma unroll
        for (int q=0; q<4; q++){
          uint4 v = dd[e1 + q];
          z0 = dot2(w2h[16+4*q+0], v.x, z0); z1 = dot2(w2h[16+4*q+1], v.y, z1);
          z0 = dot2(w2h[16+4*q+2], v.z, z0); z1 = dot2(w2h[16+4*q+3], v.w, z1);
        }
        float z = z0 + z1;
        z += __shfl_xor(z, 1);
        if (m == 0) sD2[dir*DSTR + r] = (_Float16)(dp2*z);
      }
    }
    __syncthreads();
    // ---- F: con = g_i*f + (1-f^2)*(W3 D2_i); in-wave k-sum; Heun fused ----
    {
      const uint4* d4 = (const uint4*)&sD2[i8*DSTR];  // 8-addr broadcast, conflict-free
      float a0=0.f, a1=0.f, a2=0.f, a3=0.f;
      #pragma unroll
      for (int q=0; q<16; q++){
        uint4 dv = d4[q];
        a0 = dot2(w3r[4*q+0], dv.x, a0);
        a1 = dot2(w3r[4*q+1], dv.y, a1);
        a2 = dot2(w3r[4*q+2], dv.z, a2);
        a3 = dot2(w3r[4*q+3], dv.w, a3);
      }
      float z = (a0+a1)+(a2+a3);
      float con = gi*fr + (1.f - fr*fr)*z;
      con += __shfl_xor(con, 1);              // sum over i8 (bits 0..2 of t)
      con += __shfl_xor(con, 2);
      con += __shfl_xor(con, 4);
      if (i8 == 0){
        if (mode == 0){
          sK1[a8] = con;
          sYinp[a8] = (_Float16)(sY[a8] + con);   // midpoint input for eval2
        } else {
          float yn = sY[a8] + 0.5f*(sK1[a8] + con);
          sY[a8] = yn;
          sYinp[a8] = (_Float16)yn;
        }
      }
    }
  };

  // ---- main scan over windows ----
  for (int s = 0; s < NWIN; s++){
    const float* gcur = &sG[s*LSIG];
    gi = gcur[i8];
    // build C[j][own 4 i's] in registers (compile-time branches fold; only
    // the final g-select is a runtime cndmask -> no dynamic reg indexing)
    const float4* lv4 = (const float4*)(gcur + 8);    // 16B-aligned: 144s+32
    float4 L0=lv4[0],L1=lv4[1],L2=lv4[2],L3=lv4[3],L4=lv4[4],L5=lv4[5],L6=lv4[6];
    float lv[28] = {L0.x,L0.y,L0.z,L0.w, L1.x,L1.y,L1.z,L1.w,
                    L2.x,L2.y,L2.z,L2.w, L3.x,L3.y,L3.z,L3.w,
                    L4.x,L4.y,L4.z,L4.w, L5.x,L5.y,L5.z,L5.w,
                    L6.x,L6.y,L6.z,L6.w};
    #pragma unroll
    for (int j=0; j<8; j++){
      #pragma unroll
      for (int k=0; k<4; k++){
        const int iA = k, iB = k+4;
        float vA, vB;
        if (iA < j)      vA =  lv[7*iA - (iA*(iA-1))/2 + (j-iA-1)];
        else if (iA > j) vA = -lv[7*j  - (j*(j-1))/2  + (iA-j-1)];
        else             vA = 0.f;
        if (iB < j)      vB =  lv[7*iB - (iB*(iB-1))/2 + (j-iB-1)];
        else if (iB > j) vB = -lv[7*j  - (j*(j-1))/2  + (iB-j-1)];
        else             vB = 0.f;
        c[j][k] = g ? vB : vA;
      }
    }
    EVAL(0, s);
    EVAL(1, s);
  }
  __syncthreads();
  if (t < 4){                                 // final readout (y after win 31)
    float z = sBr[t] + sSh[0];
    #pragma unroll 8
    for (int a=0; a<64; a++) z += sWr[t*64+a]*sY[a];
    outp[(b*33 + 32)*4 + t] = z;
  }
}

extern "C" void kernel_launch(void* const* d_in, const int* in_sizes, int n_in,
                              void* d_out, int out_size, void* d_ws, size_t ws_size,
                              hipStream_t stream) {
  cde_kernel<<<dim3(NBATCH), dim3(512), 0, stream>>>(
      (const float*)d_in[0],
      (const float*)d_in[1],  (const float*)d_in[2],
      (const float*)d_in[3],  (const float*)d_in[4],
      (const float*)d_in[5],  (const float*)d_in[6],
      (const float*)d_in[7],  (const float*)d_in[8],
      (const float*)d_in[9],  (const float*)d_in[10],
      (const float*)d_in[11], (const float*)d_in[12],
      (const float*)d_in[13],
      (float*)d_out);
}

// Round 2
// 312.105 us; speedup vs baseline: 1.1060x; 1.1060x over previous
//
#include <hip/hip_runtime.h>

// log-ODE Neural CDE. B=32 chains, 32 windows, Heun = 2 vector-field evals
// per window. fp32 in/out, f32 accum, f16 weights/activations (v_dot2_f32_f16).
// 512 threads/block (8 waves), one block per batch element.
//
// R11: 6-phase dataflow (R10) with cross-lane sums moved OFF the LDS pipe.
// Post-mortem R10: __shfl_xor == ds_swizzle == LDS-pipe op; 8 lockstep waves
// serialize on the LDS pipe, so +13 swizzles/eval cost +6% despite -2 phases
// (SQ_LDS_BANK_CONFLICT doubled 1.1M->2.15M, ~6 cyc/swizzle/wave).
//  * xor1/xor2 -> DPP quad_perm adds (0xB1 / 0x4E): pure VALU, 0 LDS.
//  * Phases C & F pair-split over bit 3 (partners t, t^8 share read vector):
//    each lane reads only its K-half of sH2/sD2 (8 uint4, was 16), computes
//    half-dots for BOTH pair rows, combines via DPP row_ror:8 (= xor8 in a
//    16-lane row). W3 regs = two half-rows (same 64-u32 budget).
//  * Only F's xor4 k-sum step remains a ds_swizzle (1/eval, was 23).
#define NBATCH 32
#define LPATH  513
#define NWIN   32
#define LSIG   36
#define DSTR   136   // [dir] stride sD1/sD2 (f16) = 17 uint4: conflict-free
#define FSTR   72    // [dir] stride sFh (f16) = 9 uint4

typedef unsigned int u32;
typedef _Float16 h2 __attribute__((ext_vector_type(2)));

__device__ __forceinline__ u32 pkh(float a, float b){
  return __builtin_bit_cast(u32, __builtin_amdgcn_cvt_pkrtz(a, b));
}
__device__ __forceinline__ float dot2(u32 a, u32 b, float c){
#if __has_builtin(__builtin_amdgcn_fdot2)
  return __builtin_amdgcn_fdot2(__builtin_bit_cast(h2,a),
                                __builtin_bit_cast(h2,b), c, false);
#else
  h2 x = __builtin_bit_cast(h2,a), y = __builtin_bit_cast(h2,b);
  return c + (float)x[0]*(float)y[0] + (float)x[1]*(float)y[1];
#endif
}
__device__ __forceinline__ float tanh_fast(float x){
  float e = __expf(2.f*x);
  return 1.f - 2.f/(e+1.f);
}

// DPP cross-lane adds: VALU-only, no LDS-pipe traffic.
#define DPP_XOR1 0xB1   // quad_perm [1,0,3,2]
#define DPP_XOR2 0x4E   // quad_perm [2,3,0,1]
#define DPP_ROR8 0x128  // row_ror:8 == lane^8 within each 16-lane row
template<int CTRL>
__device__ __forceinline__ float dppadd(float x){
  int v = __builtin_amdgcn_update_dpp(0, __builtin_bit_cast(int,x),
                                      CTRL, 0xF, 0xF, false);
  return x + __builtin_bit_cast(float, v);
}

extern "C" __global__ __launch_bounds__(512, 1)
void cde_kernel(const float* __restrict__ cv,
                const float* __restrict__ Wi1g, const float* __restrict__ bi1g,
                const float* __restrict__ Wi2g, const float* __restrict__ bi2g,
                const float* __restrict__ W1g,  const float* __restrict__ b1g,
                const float* __restrict__ W2g,  const float* __restrict__ b2g,
                const float* __restrict__ W3g,  const float* __restrict__ b3g,
                const float* __restrict__ Wrg,  const float* __restrict__ brg,
                const float* __restrict__ shg,
                float* __restrict__ outp)
{
  // ---- LDS (~12.5 KB) ----
  __shared__ __align__(16) float sG[NWIN*LSIG];
  __shared__ __align__(16) float sWr[256];
  __shared__ float sBr[4], sSh[1];
  __shared__ __align__(16) float sY[64];
  __shared__ float sK1[64], sLw[64];
  __shared__ __align__(16) _Float16 sYinp[64];
  __shared__ __align__(16) _Float16 sH1[128];
  __shared__ __align__(16) _Float16 sH2[128];
  __shared__ __align__(16) _Float16 sFh[8*FSTR];
  __shared__ __align__(16) _Float16 sD1[8*DSTR];
  __shared__ __align__(16) _Float16 sD2[8*DSTR];

  const int t  = threadIdx.x;        // 0..511
  const int b  = blockIdx.x;
  const int r  = t >> 2;             // 0..127 (A/B/D/E row)
  const int m  = t & 1;              // col half
  const int g  = (t >> 1) & 1;       // quarter / dir group
  const int i8 = t & 7;              // dir (C/F row-block)
  const int a8 = t >> 3;             // 0..63 (C/F col within block)
  const int h3 = a8 & 1;             // K-half for C/F pair-split (bit 3 of t)
  const int p  = i8*64 + a8;         // owned W3 row (permuted for in-wave k-sum)
  const int pE = i8*64 + (a8 & ~1);  // pair's even row
  const int pO = i8*64 + (a8 |  1);  // pair's odd row

  // ---- init readout consts ----
  if (t < 256) sWr[t] = Wrg[t];
  if (t < 4)   sBr[t] = brg[t];
  if (t == 0)  sSh[0] = shg[0];

  // ---- depth-2 Lyndon log-signatures, one window per thread (t<32) ----
  if (t < NWIN){
    const float4* cv4 = (const float4*)cv;
    const int base = (b*LPATH + t*16)*2;
    float cur[8], pre[8], acc[8], lvw[28];
    { float4 a = cv4[base], d = cv4[base+1];
      cur[0]=a.x;cur[1]=a.y;cur[2]=a.z;cur[3]=a.w;
      cur[4]=d.x;cur[5]=d.y;cur[6]=d.z;cur[7]=d.w; }
    #pragma unroll
    for (int d=0; d<8; d++){ pre[d]=0.f; acc[d]=0.f; }
    #pragma unroll
    for (int pq=0; pq<28; pq++) lvw[pq]=0.f;
    for (int w=1; w<=16; w++){
      float nxt[8], inc[8];
      { float4 a = cv4[base+2*w], d = cv4[base+2*w+1];
        nxt[0]=a.x;nxt[1]=a.y;nxt[2]=a.z;nxt[3]=a.w;
        nxt[4]=d.x;nxt[5]=d.y;nxt[6]=d.z;nxt[7]=d.w; }
      #pragma unroll
      for (int d=0; d<8; d++) inc[d] = nxt[d]-cur[d];
      int pq=0;
      #pragma unroll
      for (int i=0; i<8; i++)
        #pragma unroll
        for (int j2=i+1; j2<8; j2++){ lvw[pq] += pre[i]*inc[j2] - pre[j2]*inc[i]; pq++; }
      #pragma unroll
      for (int d=0; d<8; d++){ acc[d]+=inc[d]; pre[d]+=inc[d]; cur[d]=nxt[d]; }
    }
    float* gd = &sG[t*LSIG];
    #pragma unroll
    for (int d=0; d<8; d++) gd[d] = acc[d];
    #pragma unroll
    for (int pq=0; pq<28; pq++) gd[8+pq] = 0.5f*lvw[pq];
  }

  // ---- y0 = Wi2 @ lipswish(Wi1 @ x0 + bi1) + bi2 ----
  if (t < 64){
    float z = bi1g[t];
    #pragma unroll
    for (int d=0; d<8; d++) z += Wi1g[t*8+d] * cv[(b*LPATH)*8 + d];
    float s = 1.f/(1.f+__expf(-z));
    sLw[t] = 0.909f*z*s;
  }
  __syncthreads();
  if (t < 64){
    float z = bi2g[t];
    #pragma unroll 8
    for (int k=0; k<64; k++) z += Wi2g[t*64+k] * sLw[k];
    sY[t] = z;
    sYinp[t] = (_Float16)z;
  }
  __syncthreads();
  if (t < 4){
    float z = sBr[t] + sSh[0];
    #pragma unroll 8
    for (int a=0; a<64; a++) z += sWr[t*64+a]*sY[a];
    outp[(b*33 + 0)*4 + t] = z;
  }

  // ---- per-thread weight registers (own-quarter-first within m-half) ----
  // w1h: cols [m*32+g*16..+15] in [0..7], other quarter in [8..15].
  // w2h: cols [m*64+g*32..+31] in [0..15], other quarter in [16..31].
  // w3e/w3o: K-half h3 of rows pE/pO (pair-split for phases C and F).
  u32 w1h[16], w2h[32], w3e[32], w3o[32];
  {
    const float2* W1f2 = (const float2*)W1g;
    #pragma unroll
    for (int i=0; i<8; i++){ float2 v = W1f2[r*32 + m*16 + g*8 + i];     w1h[i]   = pkh(v.x, v.y); }
    #pragma unroll
    for (int i=0; i<8; i++){ float2 v = W1f2[r*32 + m*16 + (1-g)*8 + i]; w1h[8+i] = pkh(v.x, v.y); }
    const float2* W2f2 = (const float2*)W2g;
    #pragma unroll
    for (int i=0; i<16; i++){ float2 v = W2f2[r*64 + m*32 + g*16 + i];     w2h[i]    = pkh(v.x, v.y); }
    #pragma unroll
    for (int i=0; i<16; i++){ float2 v = W2f2[r*64 + m*32 + (1-g)*16 + i]; w2h[16+i] = pkh(v.x, v.y); }
    const float4* W3f4 = (const float4*)W3g;
    #pragma unroll
    for (int k=0; k<16; k++){
      float4 v = W3f4[pE*32 + h3*16 + k];
      w3e[2*k]   = pkh(v.x, v.y);
      w3e[2*k+1] = pkh(v.z, v.w);
    }
    #pragma unroll
    for (int k=0; k<16; k++){
      float4 v = W3f4[pO*32 + h3*16 + k];
      w3o[2*k]   = pkh(v.x, v.y);
      w3o[2*k+1] = pkh(v.z, v.w);
    }
  }
  const float b1r = b1g[r], b2r = b2g[r], b3r = b3g[p];

  float gi = 0.f;       // gcur[i8], per window
  float c[8][4];        // C[j][4g+k], per window, registers (static idx only)

  // One vector-field eval. mode 0: k1 (sK1, sYinp=y+k1, fused readout in A).
  // mode 1: k2 (Heun update fused in F).
  auto EVAL = [&](int mode, int s){
    __syncthreads();                          // sYinp (and sY) ready
    float dp1, dp2, fr;
    // ---- A: h1 = lipswish(W1 y + b1); fused y_s readout (mode 0) ----
    {
      if (mode == 0 && s > 0 && t >= 504 && t < 508){
        int o = t - 504;
        float z = sBr[o] + sSh[0];
        const float4* wr4 = (const float4*)&sWr[o*64];
        const float4* y4f = (const float4*)sY;
        #pragma unroll
        for (int q=0; q<16; q++){
          float4 w = wr4[q], y = y4f[q];
          z += w.x*y.x + w.y*y.y + w.z*y.z + w.w*y.w;
        }
        outp[(b*33 + s)*4 + o] = z;
      }
      const uint4* y4 = (const uint4*)sYinp;
      const int qa = m*4 + g*2;               // own quarter: 2 uint4
      uint4 A0 = y4[qa], A1 = y4[qa+1];
      float z0 = dot2(w1h[0], A0.x, 0.f), z1 = dot2(w1h[1], A0.y, 0.f);
      z0 = dot2(w1h[2], A0.z, z0); z1 = dot2(w1h[3], A0.w, z1);
      z0 = dot2(w1h[4], A1.x, z0); z1 = dot2(w1h[5], A1.y, z1);
      z0 = dot2(w1h[6], A1.z, z0); z1 = dot2(w1h[7], A1.w, z1);
      float z = z0 + z1;
      z = dppadd<DPP_XOR1>(z);                // sum m (VALU)
      z = dppadd<DPP_XOR2>(z);                // sum g (VALU)
      z += b1r;
      float sg = 1.f/(1.f+__expf(-z));
      dp1 = 0.909f*sg*(1.f + z*(1.f-sg));
      if ((t & 3) == 0) sH1[r] = (_Float16)(0.909f*z*sg);
    }
    __syncthreads();
    // ---- B: h2 = lipswish(W2 h1 + b2); quarter split ----
    {
      const uint4* h4 = (const uint4*)sH1;
      const int qb = m*8 + g*4;               // own quarter: 4 uint4
      float z0 = 0.f, z1 = 0.f;
      #pragma unroll
      for (int q=0; q<4; q++){
        uint4 v = h4[qb + q];
        z0 = dot2(w2h[4*q+0], v.x, z0); z1 = dot2(w2h[4*q+1], v.y, z1);
        z0 = dot2(w2h[4*q+2], v.z, z0); z1 = dot2(w2h[4*q+3], v.w, z1);
      }
      float z = z0 + z1;
      z = dppadd<DPP_XOR1>(z);
      z = dppadd<DPP_XOR2>(z);
      z += b2r;
      float sg = 1.f/(1.f+__expf(-z));
      dp2 = 0.909f*sg*(1.f + z*(1.f-sg));
      if ((t & 3) == 0) sH2[r] = (_Float16)(0.909f*z*sg);
    }
    __syncthreads();
    // ---- C: f = tanh(W3 h2 + b3); pair-split K-halves, DPP ror8 combine ----
    {
      const uint4* h4 = (const uint4*)sH2;
      float e0=0.f, e1=0.f, o0=0.f, o1=0.f;
      #pragma unroll
      for (int q=0; q<8; q++){
        uint4 hv = h4[h3*8 + q];              // own K-half only (8 uint4)
        e0 = dot2(w3e[4*q+0], hv.x, e0); e1 = dot2(w3e[4*q+1], hv.y, e1);
        e0 = dot2(w3e[4*q+2], hv.z, e0); e1 = dot2(w3e[4*q+3], hv.w, e1);
        o0 = dot2(w3o[4*q+0], hv.x, o0); o1 = dot2(w3o[4*q+1], hv.y, o1);
        o0 = dot2(w3o[4*q+2], hv.z, o0); o1 = dot2(w3o[4*q+3], hv.w, o1);
      }
      float se = dppadd<DPP_ROR8>(e0+e1);     // + partner's other-half partial
      float so = dppadd<DPP_ROR8>(o0+o1);
      fr = tanh_fast((h3 ? so : se) + b3r);   // own row: even lane->pE, odd->pO
      sFh[i8*FSTR + a8] = (_Float16)fr;
    }
    __syncthreads();
    // ---- D: P_i = W1 @ f_i ; D1_j = dp1 * sum_i C[j,i] P_i (U-fold fused) ----
    {
      const uint4* f4 = (const uint4*)sFh;
      const int q0 = m*4 + g*2, q1 = m*4 + 2 - g*2;   // own / other quarter
      float P[4];
      #pragma unroll
      for (int k=0; k<4; k++){
        const uint4* fd = &f4[(4*g + k)*9];
        uint4 A0 = fd[q0], A1 = fd[q0+1], B0 = fd[q1], B1 = fd[q1+1];
        float z0 = dot2(w1h[0], A0.x, 0.f), z1 = dot2(w1h[1], A0.y, 0.f);
        z0 = dot2(w1h[2],  A0.z, z0); z1 = dot2(w1h[3],  A0.w, z1);
        z0 = dot2(w1h[4],  A1.x, z0); z1 = dot2(w1h[5],  A1.y, z1);
        z0 = dot2(w1h[6],  A1.z, z0); z1 = dot2(w1h[7],  A1.w, z1);
        z0 = dot2(w1h[8],  B0.x, z0); z1 = dot2(w1h[9],  B0.y, z1);
        z0 = dot2(w1h[10], B0.z, z0); z1 = dot2(w1h[11], B0.w, z1);
        z0 = dot2(w1h[12], B1.x, z0); z1 = dot2(w1h[13], B1.y, z1);
        z0 = dot2(w1h[14], B1.z, z0); z1 = dot2(w1h[15], B1.w, z1);
        P[k] = dppadd<DPP_XOR1>(z0 + z1);     // sum m halves -> P_i[r]
      }
      const int own = 2*g + m;                // this lane writes j = 2*own, 2*own+1
      #pragma unroll
      for (int j=0; j<8; j++){
        float pj = c[j][0]*P[0] + c[j][1]*P[1] + c[j][2]*P[2] + c[j][3]*P[3];
        pj = dppadd<DPP_XOR2>(pj);            // add other dir-group's partial
        if ((j >> 1) == own) sD1[j*DSTR + r] = (_Float16)(dp1*pj);
      }
    }
    __syncthreads();
    // ---- E: D2_j = dp2 * (W2 @ D1_j). (r,m,g): 4 dirs x 64-col half ----
    {
      const uint4* d4 = (const uint4*)sD1;
      const int e0i = m*8 + g*4, e1i = m*8 + 4 - g*4;
      #pragma unroll
      for (int k=0; k<4; k++){
        const int dir = 4*g + k;
        const uint4* dd = &d4[dir*17];
        float z0 = 0.f, z1 = 0.f;
        #pragma unroll
        for (int q=0; q<4; q++){
          uint4 v = dd[e0i + q];
          z0 = dot2(w2h[4*q+0], v.x, z0); z1 = dot2(w2h[4*q+1], v.y, z1);
          z0 = dot2(w2h[4*q+2], v.z, z0); z1 = dot2(w2h[4*q+3], v.w, z1);
        }
        #pragma unroll
        for (int q=0; q<4; q++){
          uint4 v = dd[e1i + q];
          z0 = dot2(w2h[16+4*q+0], v.x, z0); z1 = dot2(w2h[16+4*q+1], v.y, z1);
          z0 = dot2(w2h[16+4*q+2], v.z, z0); z1 = dot2(w2h[16+4*q+3], v.w, z1);
        }
        float z = dppadd<DPP_XOR1>(z0 + z1);
        if (m == 0) sD2[dir*DSTR + r] = (_Float16)(dp2*z);
      }
    }
    __syncthreads();
    // ---- F: con = g_i*f + (1-f^2)*(W3 D2_i); pair-split reads; k-sum ----
    {
      const uint4* d4 = (const uint4*)&sD2[i8*DSTR];
      float e0=0.f, e1=0.f, o0=0.f, o1=0.f;
      #pragma unroll
      for (int q=0; q<8; q++){
        uint4 dv = d4[h3*8 + q];              // own K-half of D2[i8] (8 uint4)
        e0 = dot2(w3e[4*q+0], dv.x, e0); e1 = dot2(w3e[4*q+1], dv.y, e1);
        e0 = dot2(w3e[4*q+2], dv.z, e0); e1 = dot2(w3e[4*q+3], dv.w, e1);
        o0 = dot2(w3o[4*q+0], dv.x, o0); o1 = dot2(w3o[4*q+1], dv.y, o1);
        o0 = dot2(w3o[4*q+2], dv.z, o0); o1 = dot2(w3o[4*q+3], dv.w, o1);
      }
      float ze = dppadd<DPP_ROR8>(e0+e1);
      float zo = dppadd<DPP_ROR8>(o0+o1);
      float z  = h3 ? zo : ze;
      float con = gi*fr + (1.f - fr*fr)*z;
      con = dppadd<DPP_XOR1>(con);            // sum over i8 bit0 (VALU)
      con = dppadd<DPP_XOR2>(con);            // sum over i8 bit1 (VALU)
      con += __shfl_xor(con, 4);              // i8 bit2: the one remaining swizzle
      if (i8 == 0){
        if (mode == 0){
          sK1[a8] = con;
          sYinp[a8] = (_Float16)(sY[a8] + con);   // midpoint input for eval2
        } else {
          float yn = sY[a8] + 0.5f*(sK1[a8] + con);
          sY[a8] = yn;
          sYinp[a8] = (_Float16)yn;
        }
      }
    }
  };

  // ---- main scan over windows ----
  for (int s = 0; s < NWIN; s++){
    const float* gcur = &sG[s*LSIG];
    gi = gcur[i8];
    // build C[j][own 4 i's] in registers (compile-time branches fold; only
    // the final g-select is a runtime cndmask -> no dynamic reg indexing)
    const float4* lv4 = (const float4*)(gcur + 8);    // 16B-aligned: 144s+32
    float4 L0=lv4[0],L1=lv4[1],L2=lv4[2],L3=lv4[3],L4=lv4[4],L5=lv4[5],L6=lv4[6];
    float lv[28] = {L0.x,L0.y,L0.z,L0.w, L1.x,L1.y,L1.z,L1.w,
                    L2.x,L2.y,L2.z,L2.w, L3.x,L3.y,L3.z,L3.w,
                    L4.x,L4.y,L4.z,L4.w, L5.x,L5.y,L5.z,L5.w,
                    L6.x,L6.y,L6.z,L6.w};
    #pragma unroll
    for (int j=0; j<8; j++){
      #pragma unroll
      for (int k=0; k<4; k++){
        const int iA = k, iB = k+4;
        float vA, vB;
        if (iA < j)      vA =  lv[7*iA - (iA*(iA-1))/2 + (j-iA-1)];
        else if (iA > j) vA = -lv[7*j  - (j*(j-1))/2  + (iA-j-1)];
        else             vA = 0.f;
        if (iB < j)      vB =  lv[7*iB - (iB*(iB-1))/2 + (j-iB-1)];
        else if (iB > j) vB = -lv[7*j  - (j*(j-1))/2  + (iB-j-1)];
        else             vB = 0.f;
        c[j][k] = g ? vB : vA;
      }
    }
    EVAL(0, s);
    EVAL(1, s);
  }
  __syncthreads();
  if (t < 4){                                 // final readout (y after win 31)
    float z = sBr[t] + sSh[0];
    #pragma unroll 8
    for (int a=0; a<64; a++) z += sWr[t*64+a]*sY[a];
    outp[(b*33 + 32)*4 + t] = z;
  }
}

extern "C" void kernel_launch(void* const* d_in, const int* in_sizes, int n_in,
                              void* d_out, int out_size, void* d_ws, size_t ws_size,
                              hipStream_t stream) {
  cde_kernel<<<dim3(NBATCH), dim3(512), 0, stream>>>(
      (const float*)d_in[0],
      (const float*)d_in[1],  (const float*)d_in[2],
      (const float*)d_in[3],  (const float*)d_in[4],
      (const float*)d_in[5],  (const float*)d_in[6],
      (const float*)d_in[7],  (const float*)d_in[8],
      (const float*)d_in[9],  (const float*)d_in[10],
      (const float*)d_in[11], (const float*)d_in[12],
      (const float*)d_in[13],
      (float*)d_out);
}

// Round 3
// 306.722 us; speedup vs baseline: 1.1254x; 1.0176x over previous
//
#include <hip/hip_runtime.h>

// log-ODE Neural CDE. B=32 chains, 32 windows, Heun = 2 vector-field evals
// per window. fp32 in/out, f32 accum, f16 weights/activations (v_dot2_f32_f16).
// 512 threads/block (8 waves), one block per batch element.
//
// R12: pair-split (bit3) K-slicing extended from C/F to A/B/D/E.
// Post-mortem R11: SQ_LDS_BANK_CONFLICT identical R10/R11 -> counter is
// structural 2-way read aliasing (free); the R11 win was removing dependent
// ds_swizzle LATENCY. Remaining big LDS consumer: 70 ds_read_b128/lane/eval,
// of which D(16)+E(32) have bit3-pair lanes reading IDENTICAL addresses.
//  * w1h/w2h re-layout: lane holds (m,hb)-K-slice of BOTH pair rows
//    (rowE=r&~2, rowO=r|2); same reg budget. Lane reads only its slice,
//    computes both rows' partials, combines via ROR8(hb)+XOR1(m) DPP.
//  * Reads/lane/eval 70 -> 46 (D 16->8, E 32->16).
//  * D c-combine: 4 j's via per-window cJ[4][4] (m-select folded at build,
//    static reg indices) instead of 8 -> -16 fma -4 DPP.
#define NBATCH 32
#define LPATH  513
#define NWIN   32
#define LSIG   36
#define DSTR   136   // [dir] stride sD1/sD2 (f16) = 17 uint4
#define FSTR   72    // [dir] stride sFh (f16) = 9 uint4

typedef unsigned int u32;
typedef _Float16 h2 __attribute__((ext_vector_type(2)));

__device__ __forceinline__ u32 pkh(float a, float b){
  return __builtin_bit_cast(u32, __builtin_amdgcn_cvt_pkrtz(a, b));
}
__device__ __forceinline__ float dot2(u32 a, u32 b, float c){
#if __has_builtin(__builtin_amdgcn_fdot2)
  return __builtin_amdgcn_fdot2(__builtin_bit_cast(h2,a),
                                __builtin_bit_cast(h2,b), c, false);
#else
  h2 x = __builtin_bit_cast(h2,a), y = __builtin_bit_cast(h2,b);
  return c + (float)x[0]*(float)y[0] + (float)x[1]*(float)y[1];
#endif
}
__device__ __forceinline__ float tanh_fast(float x){
  float e = __expf(2.f*x);
  return 1.f - 2.f/(e+1.f);
}

// DPP cross-lane adds: VALU-only, no LDS-pipe traffic.
#define DPP_XOR1 0xB1   // quad_perm [1,0,3,2]
#define DPP_XOR2 0x4E   // quad_perm [2,3,0,1]
#define DPP_ROR8 0x128  // row_ror:8 == lane^8 within each 16-lane row
template<int CTRL>
__device__ __forceinline__ float dppadd(float x){
  int v = __builtin_amdgcn_update_dpp(0, __builtin_bit_cast(int,x),
                                      CTRL, 0xF, 0xF, false);
  return x + __builtin_bit_cast(float, v);
}

extern "C" __global__ __launch_bounds__(512, 1)
void cde_kernel(const float* __restrict__ cv,
                const float* __restrict__ Wi1g, const float* __restrict__ bi1g,
                const float* __restrict__ Wi2g, const float* __restrict__ bi2g,
                const float* __restrict__ W1g,  const float* __restrict__ b1g,
                const float* __restrict__ W2g,  const float* __restrict__ b2g,
                const float* __restrict__ W3g,  const float* __restrict__ b3g,
                const float* __restrict__ Wrg,  const float* __restrict__ brg,
                const float* __restrict__ shg,
                float* __restrict__ outp)
{
  // ---- LDS (~12.5 KB) ----
  __shared__ __align__(16) float sG[NWIN*LSIG];
  __shared__ __align__(16) float sWr[256];
  __shared__ float sBr[4], sSh[1];
  __shared__ __align__(16) float sY[64];
  __shared__ float sK1[64], sLw[64];
  __shared__ __align__(16) _Float16 sYinp[64];
  __shared__ __align__(16) _Float16 sH1[128];
  __shared__ __align__(16) _Float16 sH2[128];
  __shared__ __align__(16) _Float16 sFh[8*FSTR];
  __shared__ __align__(16) _Float16 sD1[8*DSTR];
  __shared__ __align__(16) _Float16 sD2[8*DSTR];

  const int t  = threadIdx.x;        // 0..511
  const int b  = blockIdx.x;
  const int r  = t >> 2;             // 0..127 (A/B/D/E row)
  const int m  = t & 1;              // col half
  const int g  = (t >> 1) & 1;       // dir group (D/E: 4 dirs each)
  const int hb = (t >> 3) & 1;       // bit3: pair K-slice selector (== r&2)>>1
  const int i8 = t & 7;              // dir (C/F row-block)
  const int a8 = t >> 3;             // 0..63 (C/F col within block)
  const int p  = i8*64 + a8;         // owned W3 row (permuted for in-wave k-sum)
  const int pE = i8*64 + (a8 & ~1);  // C/F pair's even row
  const int pO = i8*64 + (a8 |  1);  // C/F pair's odd row
  const int rE = r & ~2;             // A/B/D/E pair's even row
  const int rO = r |  2;             // A/B/D/E pair's odd row

  // ---- init readout consts ----
  if (t < 256) sWr[t] = Wrg[t];
  if (t < 4)   sBr[t] = brg[t];
  if (t == 0)  sSh[0] = shg[0];

  // ---- depth-2 Lyndon log-signatures, one window per thread (t<32) ----
  if (t < NWIN){
    const float4* cv4 = (const float4*)cv;
    const int base = (b*LPATH + t*16)*2;
    float cur[8], pre[8], acc[8], lvw[28];
    { float4 a = cv4[base], d = cv4[base+1];
      cur[0]=a.x;cur[1]=a.y;cur[2]=a.z;cur[3]=a.w;
      cur[4]=d.x;cur[5]=d.y;cur[6]=d.z;cur[7]=d.w; }
    #pragma unroll
    for (int d=0; d<8; d++){ pre[d]=0.f; acc[d]=0.f; }
    #pragma unroll
    for (int pq=0; pq<28; pq++) lvw[pq]=0.f;
    for (int w=1; w<=16; w++){
      float nxt[8], inc[8];
      { float4 a = cv4[base+2*w], d = cv4[base+2*w+1];
        nxt[0]=a.x;nxt[1]=a.y;nxt[2]=a.z;nxt[3]=a.w;
        nxt[4]=d.x;nxt[5]=d.y;nxt[6]=d.z;nxt[7]=d.w; }
      #pragma unroll
      for (int d=0; d<8; d++) inc[d] = nxt[d]-cur[d];
      int pq=0;
      #pragma unroll
      for (int i=0; i<8; i++)
        #pragma unroll
        for (int j2=i+1; j2<8; j2++){ lvw[pq] += pre[i]*inc[j2] - pre[j2]*inc[i]; pq++; }
      #pragma unroll
      for (int d=0; d<8; d++){ acc[d]+=inc[d]; pre[d]+=inc[d]; cur[d]=nxt[d]; }
    }
    float* gd = &sG[t*LSIG];
    #pragma unroll
    for (int d=0; d<8; d++) gd[d] = acc[d];
    #pragma unroll
    for (int pq=0; pq<28; pq++) gd[8+pq] = 0.5f*lvw[pq];
  }

  // ---- y0 = Wi2 @ lipswish(Wi1 @ x0 + bi1) + bi2 ----
  if (t < 64){
    float z = bi1g[t];
    #pragma unroll
    for (int d=0; d<8; d++) z += Wi1g[t*8+d] * cv[(b*LPATH)*8 + d];
    float s = 1.f/(1.f+__expf(-z));
    sLw[t] = 0.909f*z*s;
  }
  __syncthreads();
  if (t < 64){
    float z = bi2g[t];
    #pragma unroll 8
    for (int k=0; k<64; k++) z += Wi2g[t*64+k] * sLw[k];
    sY[t] = z;
    sYinp[t] = (_Float16)z;
  }
  __syncthreads();
  if (t < 4){
    float z = sBr[t] + sSh[0];
    #pragma unroll 8
    for (int a=0; a<64; a++) z += sWr[t*64+a]*sY[a];
    outp[(b*33 + 0)*4 + t] = z;
  }

  // ---- per-thread weight registers, pair-row (m,hb)-slice layout ----
  // w1h: [0..7]  = W1 row rE, cols m*32+hb*16 .. +15 (8 u32)
  //      [8..15] = W1 row rO, same cols.
  // w2h: [0..15] = W2 row rE, cols m*64+hb*32 .. +31 (16 u32)
  //      [16..31]= W2 row rO, same cols.
  // w3e/w3o: K-half h3 of rows pE/pO (C/F pair-split, unchanged).
  u32 w1h[16], w2h[32], w3e[32], w3o[32];
  {
    const float2* W1f2 = (const float2*)W1g;
    #pragma unroll
    for (int i=0; i<8; i++){ float2 v = W1f2[rE*32 + m*16 + hb*8 + i]; w1h[i]   = pkh(v.x, v.y); }
    #pragma unroll
    for (int i=0; i<8; i++){ float2 v = W1f2[rO*32 + m*16 + hb*8 + i]; w1h[8+i] = pkh(v.x, v.y); }
    const float2* W2f2 = (const float2*)W2g;
    #pragma unroll
    for (int i=0; i<16; i++){ float2 v = W2f2[rE*64 + m*32 + hb*16 + i]; w2h[i]    = pkh(v.x, v.y); }
    #pragma unroll
    for (int i=0; i<16; i++){ float2 v = W2f2[rO*64 + m*32 + hb*16 + i]; w2h[16+i] = pkh(v.x, v.y); }
    const float4* W3f4 = (const float4*)W3g;
    #pragma unroll
    for (int k=0; k<16; k++){
      float4 v = W3f4[pE*32 + (a8&1)*16 + k];
      w3e[2*k]   = pkh(v.x, v.y);
      w3e[2*k+1] = pkh(v.z, v.w);
    }
    #pragma unroll
    for (int k=0; k<16; k++){
      float4 v = W3f4[pO*32 + (a8&1)*16 + k];
      w3o[2*k]   = pkh(v.x, v.y);
      w3o[2*k+1] = pkh(v.z, v.w);
    }
  }
  const float b1r = b1g[r], b2r = b2g[r], b3r = b3g[p];

  float gi = 0.f;       // gcur[i8], per window
  // cJ[q][k]: C[j(q)][4g+k] with j(q) = 2m + (q&1) + (q>>1)*4 (m folded at
  // build via cndmask; all register indices static).
  float cJ[4][4];

  // One vector-field eval. mode 0: k1 (sK1, sYinp=y+k1, fused readout in A).
  // mode 1: k2 (Heun update fused in F).
  auto EVAL = [&](int mode, int s){
    __syncthreads();                          // sYinp (and sY) ready
    float dp1, dp2, fr;
    // ---- A: h1 = lipswish(W1 y + b1); pair rows, (m,hb) slice ----
    {
      if (mode == 0 && s > 0 && t >= 504 && t < 508){
        int o = t - 504;
        float z = sBr[o] + sSh[0];
        const float4* wr4 = (const float4*)&sWr[o*64];
        const float4* y4f = (const float4*)sY;
        #pragma unroll
        for (int q=0; q<16; q++){
          float w0 = wr4[q].x, w1 = wr4[q].y, w2 = wr4[q].z, w3 = wr4[q].w;
          float y0 = y4f[q].x, y1 = y4f[q].y, y2 = y4f[q].z, y3 = y4f[q].w;
          z += w0*y0 + w1*y1 + w2*y2 + w3*y3;
        }
        outp[(b*33 + s)*4 + o] = z;
      }
      const uint4* y4 = (const uint4*)sYinp;
      const int qa = m*4 + hb*2;              // (m*32+hb*16)/8
      uint4 A0 = y4[qa], A1 = y4[qa+1];
      float e0 = dot2(w1h[0], A0.x, 0.f), e1 = dot2(w1h[1], A0.y, 0.f);
      e0 = dot2(w1h[2], A0.z, e0); e1 = dot2(w1h[3], A0.w, e1);
      e0 = dot2(w1h[4], A1.x, e0); e1 = dot2(w1h[5], A1.y, e1);
      e0 = dot2(w1h[6], A1.z, e0); e1 = dot2(w1h[7], A1.w, e1);
      float o0 = dot2(w1h[8],  A0.x, 0.f), o1 = dot2(w1h[9],  A0.y, 0.f);
      o0 = dot2(w1h[10], A0.z, o0); o1 = dot2(w1h[11], A0.w, o1);
      o0 = dot2(w1h[12], A1.x, o0); o1 = dot2(w1h[13], A1.y, o1);
      o0 = dot2(w1h[14], A1.z, o0); o1 = dot2(w1h[15], A1.w, o1);
      float zE = dppadd<DPP_ROR8>(e0+e1);     // + partner slice (hb)
      float zO = dppadd<DPP_ROR8>(o0+o1);
      zE = dppadd<DPP_XOR1>(zE);              // + other m half
      zO = dppadd<DPP_XOR1>(zO);
      float z = (hb ? zO : zE) + b1r;         // own row (r&2 == hb<<1)
      float sg = 1.f/(1.f+__expf(-z));
      dp1 = 0.909f*sg*(1.f + z*(1.f-sg));
      if ((t & 3) == 0) sH1[r] = (_Float16)(0.909f*z*sg);
    }
    __syncthreads();
    // ---- B: h2 = lipswish(W2 h1 + b2); pair rows, (m,hb) slice ----
    {
      const uint4* h4 = (const uint4*)sH1;
      const int qb = m*8 + hb*4;              // (m*64+hb*32)/8
      float e0=0.f, e1=0.f, o0=0.f, o1=0.f;
      #pragma unroll
      for (int q=0; q<4; q++){
        uint4 v = h4[qb + q];
        e0 = dot2(w2h[4*q+0], v.x, e0); e1 = dot2(w2h[4*q+1], v.y, e1);
        e0 = dot2(w2h[4*q+2], v.z, e0); e1 = dot2(w2h[4*q+3], v.w, e1);
        o0 = dot2(w2h[16+4*q+0], v.x, o0); o1 = dot2(w2h[16+4*q+1], v.y, o1);
        o0 = dot2(w2h[16+4*q+2], v.z, o0); o1 = dot2(w2h[16+4*q+3], v.w, o1);
      }
      float zE = dppadd<DPP_ROR8>(e0+e1);
      float zO = dppadd<DPP_ROR8>(o0+o1);
      zE = dppadd<DPP_XOR1>(zE);
      zO = dppadd<DPP_XOR1>(zO);
      float z = (hb ? zO : zE) + b2r;
      float sg = 1.f/(1.f+__expf(-z));
      dp2 = 0.909f*sg*(1.f + z*(1.f-sg));
      if ((t & 3) == 0) sH2[r] = (_Float16)(0.909f*z*sg);
    }
    __syncthreads();
    // ---- C: f = tanh(W3 h2 + b3); pair-split K-halves (unchanged) ----
    {
      const uint4* h4 = (const uint4*)sH2;
      float e0=0.f, e1=0.f, o0=0.f, o1=0.f;
      #pragma unroll
      for (int q=0; q<8; q++){
        uint4 hv = h4[(a8&1)*8 + q];          // own K-half only (8 uint4)
        e0 = dot2(w3e[4*q+0], hv.x, e0); e1 = dot2(w3e[4*q+1], hv.y, e1);
        e0 = dot2(w3e[4*q+2], hv.z, e0); e1 = dot2(w3e[4*q+3], hv.w, e1);
        o0 = dot2(w3o[4*q+0], hv.x, o0); o1 = dot2(w3o[4*q+1], hv.y, o1);
        o0 = dot2(w3o[4*q+2], hv.z, o0); o1 = dot2(w3o[4*q+3], hv.w, o1);
      }
      float se = dppadd<DPP_ROR8>(e0+e1);     // + partner's other-half partial
      float so = dppadd<DPP_ROR8>(o0+o1);
      fr = tanh_fast(((a8&1) ? so : se) + b3r);
      sFh[i8*FSTR + a8] = (_Float16)fr;
    }
    __syncthreads();
    // ---- D: P_i = W1 @ f_i ; D1_j = dp1 * sum_i C[j,i] P_i ----
    // Pair rows + (m,hb) slice: 2 uint4/dir (was 4). cJ combine: 4 j's.
    {
      const uint4* f4 = (const uint4*)sFh;
      float P[4];
      #pragma unroll
      for (int k=0; k<4; k++){
        const uint4* fd = &f4[(4*g + k)*9 + m*4 + hb*2];
        uint4 A0 = fd[0], A1 = fd[1];
        float e0 = dot2(w1h[0], A0.x, 0.f), e1 = dot2(w1h[1], A0.y, 0.f);
        e0 = dot2(w1h[2], A0.z, e0); e1 = dot2(w1h[3], A0.w, e1);
        e0 = dot2(w1h[4], A1.x, e0); e1 = dot2(w1h[5], A1.y, e1);
        e0 = dot2(w1h[6], A1.z, e0); e1 = dot2(w1h[7], A1.w, e1);
        float o0 = dot2(w1h[8],  A0.x, 0.f), o1 = dot2(w1h[9],  A0.y, 0.f);
        o0 = dot2(w1h[10], A0.z, o0); o1 = dot2(w1h[11], A0.w, o1);
        o0 = dot2(w1h[12], A1.x, o0); o1 = dot2(w1h[13], A1.y, o1);
        o0 = dot2(w1h[14], A1.z, o0); o1 = dot2(w1h[15], A1.w, o1);
        float pe = dppadd<DPP_ROR8>(e0+e1);
        float po = dppadd<DPP_ROR8>(o0+o1);
        pe = dppadd<DPP_XOR1>(pe);
        po = dppadd<DPP_XOR1>(po);
        P[k] = hb ? po : pe;                  // P_dir[r], own row
      }
      // 4 j's: q -> j = 2m + (q&1) + (q>>1)*4; own writes at (q>>1)==g.
      #pragma unroll
      for (int q=0; q<4; q++){
        float pj = cJ[q][0]*P[0] + cJ[q][1]*P[1] + cJ[q][2]*P[2] + cJ[q][3]*P[3];
        pj = dppadd<DPP_XOR2>(pj);            // + other dir-group's partial
        if ((q >> 1) == g){
          int j = 2*m + (q & 1) + (q >> 1)*4;
          sD1[j*DSTR + r] = (_Float16)(dp1*pj);
        }
      }
    }
    __syncthreads();
    // ---- E: D2_j = dp2 * (W2 @ D1_j); pair rows, (m,hb) slice: 4 uint4/dir ----
    {
      const uint4* d4 = (const uint4*)sD1;
      #pragma unroll
      for (int k=0; k<4; k++){
        const int dir = 4*g + k;
        const uint4* dd = &d4[dir*17 + m*8 + hb*4];
        float e0=0.f, e1=0.f, o0=0.f, o1=0.f;
        #pragma unroll
        for (int q=0; q<4; q++){
          uint4 v = dd[q];
          e0 = dot2(w2h[4*q+0], v.x, e0); e1 = dot2(w2h[4*q+1], v.y, e1);
          e0 = dot2(w2h[4*q+2], v.z, e0); e1 = dot2(w2h[4*q+3], v.w, e1);
          o0 = dot2(w2h[16+4*q+0], v.x, o0); o1 = dot2(w2h[16+4*q+1], v.y, o1);
          o0 = dot2(w2h[16+4*q+2], v.z, o0); o1 = dot2(w2h[16+4*q+3], v.w, o1);
        }
        float zE = dppadd<DPP_ROR8>(e0+e1);
        float zO = dppadd<DPP_ROR8>(o0+o1);
        zE = dppadd<DPP_XOR1>(zE);
        zO = dppadd<DPP_XOR1>(zO);
        float z = hb ? zO : zE;               // own row
        if (m == 0) sD2[dir*DSTR + r] = (_Float16)(dp2*z);
      }
    }
    __syncthreads();
    // ---- F: con = g_i*f + (1-f^2)*(W3 D2_i); pair-split reads; k-sum ----
    {
      const uint4* d4 = (const uint4*)&sD2[i8*DSTR];
      float e0=0.f, e1=0.f, o0=0.f, o1=0.f;
      #pragma unroll
      for (int q=0; q<8; q++){
        uint4 dv = d4[(a8&1)*8 + q];          // own K-half of D2[i8] (8 uint4)
        e0 = dot2(w3e[4*q+0], dv.x, e0); e1 = dot2(w3e[4*q+1], dv.y, e1);
        e0 = dot2(w3e[4*q+2], dv.z, e0); e1 = dot2(w3e[4*q+3], dv.w, e1);
        o0 = dot2(w3o[4*q+0], dv.x, o0); o1 = dot2(w3o[4*q+1], dv.y, o1);
        o0 = dot2(w3o[4*q+2], dv.z, o0); o1 = dot2(w3o[4*q+3], dv.w, o1);
      }
      float ze = dppadd<DPP_ROR8>(e0+e1);
      float zo = dppadd<DPP_ROR8>(o0+o1);
      float z  = (a8&1) ? zo : ze;
      float con = gi*fr + (1.f - fr*fr)*z;
      con = dppadd<DPP_XOR1>(con);            // sum over i8 bit0 (VALU)
      con = dppadd<DPP_XOR2>(con);            // sum over i8 bit1 (VALU)
      con += __shfl_xor(con, 4);              // i8 bit2: the one remaining swizzle
      if (i8 == 0){
        if (mode == 0){
          sK1[a8] = con;
          sYinp[a8] = (_Float16)(sY[a8] + con);   // midpoint input for eval2
        } else {
          float yn = sY[a8] + 0.5f*(sK1[a8] + con);
          sY[a8] = yn;
          sYinp[a8] = (_Float16)yn;
        }
      }
    }
  };

  // ---- main scan over windows ----
  for (int s = 0; s < NWIN; s++){
    const float* gcur = &sG[s*LSIG];
    gi = gcur[i8];
    // build cJ[q][k] = C[j(q)][4g+k], j(q) = 2m + (q&1) + (q>>1)*4.
    // All lv/register indices compile-time; m,g folded via cndmask selects.
    const float4* lv4 = (const float4*)(gcur + 8);    // 16B-aligned: 144s+32
    float4 L0=lv4[0],L1=lv4[1],L2=lv4[2],L3=lv4[3],L4=lv4[4],L5=lv4[5],L6=lv4[6];
    float lv[28] = {L0.x,L0.y,L0.z,L0.w, L1.x,L1.y,L1.z,L1.w,
                    L2.x,L2.y,L2.z,L2.w, L3.x,L3.y,L3.z,L3.w,
                    L4.x,L4.y,L4.z,L4.w, L5.x,L5.y,L5.z,L5.w,
                    L6.x,L6.y,L6.z,L6.w};
    #pragma unroll
    for (int q=0; q<4; q++){
      const int j0 = (q & 1) + (q >> 1)*4;    // m=0 candidate j
      const int j1 = j0 + 2;                  // m=1 candidate j
      #pragma unroll
      for (int k=0; k<4; k++){
        float v00, v01, v10, v11;             // v[m][g]
        { const int i = k;                    // g=0 dirs
          v00 = (i < j0) ?  lv[7*i - (i*(i-1))/2 + (j0-i-1)]
              : (i > j0) ? -lv[7*j0 - (j0*(j0-1))/2 + (i-j0-1)] : 0.f;
          v10 = (i < j1) ?  lv[7*i - (i*(i-1))/2 + (j1-i-1)]
              : (i > j1) ? -lv[7*j1 - (j1*(j1-1))/2 + (i-j1-1)] : 0.f; }
        { const int i = k + 4;                // g=1 dirs
          v01 = (i < j0) ?  lv[7*i - (i*(i-1))/2 + (j0-i-1)]
              : (i > j0) ? -lv[7*j0 - (j0*(j0-1))/2 + (i-j0-1)] : 0.f;
          v11 = (i < j1) ?  lv[7*i - (i*(i-1))/2 + (j1-i-1)]
              : (i > j1) ? -lv[7*j1 - (j1*(j1-1))/2 + (i-j1-1)] : 0.f; }
        float vm0 = g ? v01 : v00;
        float vm1 = g ? v11 : v10;
        cJ[q][k] = m ? vm1 : vm0;
      }
    }
    EVAL(0, s);
    EVAL(1, s);
  }
  __syncthreads();
  if (t < 4){                                 // final readout (y after win 31)
    float z = sBr[t] + sSh[0];
    #pragma unroll 8
    for (int a=0; a<64; a++) z += sWr[t*64+a]*sY[a];
    outp[(b*33 + 32)*4 + t] = z;
  }
}

extern "C" void kernel_launch(void* const* d_in, const int* in_sizes, int n_in,
                              void* d_out, int out_size, void* d_ws, size_t ws_size,
                              hipStream_t stream) {
  cde_kernel<<<dim3(NBATCH), dim3(512), 0, stream>>>(
      (const float*)d_in[0],
      (const float*)d_in[1],  (const float*)d_in[2],
      (const float*)d_in[3],  (const float*)d_in[4],
      (const float*)d_in[5],  (const float*)d_in[6],
      (const float*)d_in[7],  (const float*)d_in[8],
      (const float*)d_in[9],  (const float*)d_in[10],
      (const float*)d_in[11], (const float*)d_in[12],
      (const float*)d_in[13],
      (float*)d_out);
}